// Round 1
// baseline (150.937 us; speedup 1.0000x reference)
//
#include <hip/hip_runtime.h>

// Fast HW transcendentals (v_exp_f32 / v_log_f32 / v_rcp_f32).
__device__ __forceinline__ float fexp2(float x) { return __builtin_amdgcn_exp2f(x); }
__device__ __forceinline__ float flog2(float x) { return __builtin_amdgcn_logf(x); }
__device__ __forceinline__ float frcp (float x) { return __builtin_amdgcn_rcpf(x); }
__device__ __forceinline__ float ffma (float a, float b, float c) { return __builtin_fmaf(a, b, c); }

#define LAB_EPS   0.008856f
#define F16_116   0.13793103448275862f   // 16/116
#define INV_KAPPA 0.12841915central      // placeholder (not used; see literal below)

// Each thread handles P=8 points. Block = 256 threads.
// Folded algebra (done once per block into LDS):
//   out = x@A + h@W2p + back_lab@Wf_bot + cvec
//   A    = w_lin @ (Wc_top @ Wf_top)               [3x3]
//   W2p  = w_seq2 @ (Wc_bot @ Wf_top)              [64x3]
//   cvec = b_lin@G + b_seq2@H3 + b_comb@Wf_top + b_final
__global__ __launch_bounds__(256) void fused_kernel(
    const float* __restrict__ x,
    const float* __restrict__ w_seq1, const float* __restrict__ b_seq1,
    const float* __restrict__ w_seq2, const float* __restrict__ b_seq2,
    const float* __restrict__ w_lin,  const float* __restrict__ b_lin,
    const float* __restrict__ w_comb, const float* __restrict__ b_comb,
    const float* __restrict__ w_logd, const float* __restrict__ b_logd,
    const float* __restrict__ w_final,const float* __restrict__ b_final,
    float* __restrict__ out, int n)
{
    __shared__ float4 wlds[128];   // per-j packed: {w1_0j,w1_1j,w1_2j,b1j} {w2p_j0,w2p_j1,w2p_j2,0}
    __shared__ float  smlds[33];   // A[9], Wf_bot[9], w_logd[9], b_logd[3], cvec[3]

    const int tid = threadIdx.x;
    if (tid < 64) {
        const int j = tid;
        float H3[9];
        for (int i = 0; i < 3; ++i)
            for (int c = 0; c < 3; ++c) {
                float h = 0.f;
                for (int m = 0; m < 3; ++m) h += w_comb[(i + 3) * 3 + m] * w_final[m * 3 + c];
                H3[i * 3 + c] = h;
            }
        const float w0 = w_seq2[j * 3 + 0], w1 = w_seq2[j * 3 + 1], w2 = w_seq2[j * 3 + 2];
        wlds[2 * j]     = make_float4(w_seq1[j], w_seq1[64 + j], w_seq1[128 + j], b_seq1[j]);
        wlds[2 * j + 1] = make_float4(w0 * H3[0] + w1 * H3[3] + w2 * H3[6],
                                      w0 * H3[1] + w1 * H3[4] + w2 * H3[7],
                                      w0 * H3[2] + w1 * H3[5] + w2 * H3[8], 0.f);
        if (j == 0) {
            float G[9];
            for (int i = 0; i < 3; ++i)
                for (int c = 0; c < 3; ++c) {
                    float gg = 0.f;
                    for (int m = 0; m < 3; ++m) gg += w_comb[i * 3 + m] * w_final[m * 3 + c];
                    G[i * 3 + c] = gg;
                }
            for (int k = 0; k < 3; ++k)
                for (int c = 0; c < 3; ++c) {
                    float s = 0.f;
                    for (int i = 0; i < 3; ++i) s += w_lin[k * 3 + i] * G[i * 3 + c];
                    smlds[k * 3 + c]      = s;                          // A
                    smlds[9  + k * 3 + c] = w_final[(k + 3) * 3 + c];   // Wf_bot
                    smlds[18 + k * 3 + c] = w_logd[k * 3 + c];
                }
            for (int c = 0; c < 3; ++c) {
                float s = b_final[c];
                for (int i = 0; i < 3; ++i)
                    s += b_lin[i] * G[i * 3 + c] + b_seq2[i] * H3[i * 3 + c]
                       + b_comb[i] * w_final[i * 3 + c];
                smlds[27 + c] = b_logd[c];
                smlds[30 + c] = s;                                      // cvec
            }
        }
    }
    __syncthreads();

    float A[9], Wfb[9], Wld[9], bld[3], cv[3];
#pragma unroll
    for (int i = 0; i < 9; ++i) { A[i] = smlds[i]; Wfb[i] = smlds[9 + i]; Wld[i] = smlds[18 + i]; }
#pragma unroll
    for (int i = 0; i < 3; ++i) { bld[i] = smlds[27 + i]; cv[i] = smlds[30 + i]; }

    const int g = blockIdx.x * blockDim.x + tid;
    if (g * 8 >= n) return;

    const float4* xin = reinterpret_cast<const float4*>(x) + (size_t)g * 6;
    const float4 v0 = xin[0], v1 = xin[1], v2 = xin[2], v3 = xin[3], v4 = xin[4], v5 = xin[5];
    float xs[8][3] = {
        {v0.x, v0.y, v0.z}, {v0.w, v1.x, v1.y}, {v1.z, v1.w, v2.x}, {v2.y, v2.z, v2.w},
        {v3.x, v3.y, v3.z}, {v3.w, v4.x, v4.y}, {v4.z, v4.w, v5.x}, {v5.y, v5.z, v5.w}};

    float acc[8][3];
#pragma unroll
    for (int p = 0; p < 8; ++p) { acc[p][0] = 0.f; acc[p][1] = 0.f; acc[p][2] = 0.f; }

    // hidden layer: h_j = tanh(x . w1_j + b1_j); acc += h_j * w2p_j
#pragma unroll 4
    for (int j = 0; j < 64; ++j) {
        const float4 wa = wlds[2 * j];
        const float4 wb = wlds[2 * j + 1];
#pragma unroll
        for (int p = 0; p < 8; ++p) {
            float t = ffma(xs[p][0], wa.x, ffma(xs[p][1], wa.y, ffma(xs[p][2], wa.z, wa.w)));
            float e = fexp2(t * 2.8853900817779268f);   // e^(2t)
            float r = frcp(e + 1.0f);
            float h = ffma(-2.0f, r, 1.0f);             // tanh(t), saturates cleanly
            acc[p][0] = ffma(h, wb.x, acc[p][0]);
            acc[p][1] = ffma(h, wb.y, acc[p][1]);
            acc[p][2] = ffma(h, wb.z, acc[p][2]);
        }
    }

    float ov[24];
#pragma unroll
    for (int p = 0; p < 8; ++p) {
        const float L = xs[p][0], aa = xs[p][1], bb = xs[p][2];
        // ---- lab2rgb(x) ----
        const float fy = (L + 16.0f) * (1.0f / 116.0f);
        const float fx = ffma(aa,  0.002f, fy);
        const float fz = ffma(bb, -0.005f, fy);
        float rgb[3];
        {
            const float f3x = fx * fx * fx, f3y = fy * fy * fy, f3z = fz * fz * fz;
            const float tx = f3x > LAB_EPS ? f3x : (fx - F16_116) * (1.0f / 7.787f);
            const float ty = f3y > LAB_EPS ? f3y : (fy - F16_116) * (1.0f / 7.787f);
            const float tz = f3z > LAB_EPS ? f3z : (fz - F16_116) * (1.0f / 7.787f);
            const float X = tx * 0.95047f, Y = ty, Z = tz * 1.08883f;
            const float linv[3] = {
                 3.2404542f * X - 1.5371385f * Y - 0.4985314f * Z,
                -0.9692660f * X + 1.8760108f * Y + 0.0415560f * Z,
                 0.0556434f * X - 0.2040259f * Y + 1.0572252f * Z};
#pragma unroll
            for (int c = 0; c < 3; ++c) {
                const float cc = linv[c];
                const float lo = 12.92f * cc;
                const float hi = ffma(1.055f,
                                      fexp2(flog2(fmaxf(cc, 0.0031308f)) * (1.0f / 2.4f)),
                                      -0.055f);
                rgb[c] = cc <= 0.0031308f ? lo : hi;
            }
        }
        // ---- -log10 -> @w_logd+b -> 10^ -> srgb_to_linear ----
        const float ld0 = -0.30102999566398120f * flog2(rgb[0]);
        const float ld1 = -0.30102999566398120f * flog2(rgb[1]);
        const float ld2 = -0.30102999566398120f * flog2(rgb[2]);
        float lin2[3];
#pragma unroll
        for (int c = 0; c < 3; ++c) {
            const float mp  = ffma(ld0, Wld[c], ffma(ld1, Wld[3 + c], ffma(ld2, Wld[6 + c], bld[c])));
            const float r10 = fexp2(mp * 3.3219280948873623f);   // 10^mp
            const float lo  = r10 * (1.0f / 12.92f);
            const float base = (fmaxf(r10, 0.04045f) + 0.055f) * (1.0f / 1.055f);
            const float hi  = fexp2(2.4f * flog2(base));
            lin2[c] = r10 <= 0.04045f ? lo : hi;
        }
        // ---- rgb2lab ----
        const float X2 = (0.412453f * lin2[0] + 0.357580f * lin2[1] + 0.180423f * lin2[2]) * (1.0f / 0.95047f);
        const float Y2 =  0.212671f * lin2[0] + 0.715160f * lin2[1] + 0.072169f * lin2[2];
        const float Z2 = (0.019334f * lin2[0] + 0.119193f * lin2[1] + 0.950227f * lin2[2]) * (1.0f / 1.08883f);
        const float fX = X2 > LAB_EPS ? fexp2(flog2(fmaxf(X2, LAB_EPS)) * (1.0f / 3.0f)) : ffma(7.787f, X2, F16_116);
        const float fY = Y2 > LAB_EPS ? fexp2(flog2(fmaxf(Y2, LAB_EPS)) * (1.0f / 3.0f)) : ffma(7.787f, Y2, F16_116);
        const float fZ = Z2 > LAB_EPS ? fexp2(flog2(fmaxf(Z2, LAB_EPS)) * (1.0f / 3.0f)) : ffma(7.787f, Z2, F16_116);
        const float bL = ffma(116.0f, fY, -16.0f);
        const float bA = 500.0f * (fX - fY);
        const float bB = 200.0f * (fY - fZ);
        // ---- final combine (folded) ----
#pragma unroll
        for (int c = 0; c < 3; ++c) {
            float o = cv[c];
            o = ffma(L,  A[c],     o);
            o = ffma(aa, A[3 + c], o);
            o = ffma(bb, A[6 + c], o);
            o += acc[p][c];
            o = ffma(bL, Wfb[c],     o);
            o = ffma(bA, Wfb[3 + c], o);
            o = ffma(bB, Wfb[6 + c], o);
            ov[p * 3 + c] = o;
        }
    }

    float4* op = reinterpret_cast<float4*>(out) + (size_t)g * 6;
#pragma unroll
    for (int i = 0; i < 6; ++i)
        op[i] = make_float4(ov[4 * i], ov[4 * i + 1], ov[4 * i + 2], ov[4 * i + 3]);
}

extern "C" void kernel_launch(void* const* d_in, const int* in_sizes, int n_in,
                              void* d_out, int out_size, void* d_ws, size_t ws_size,
                              hipStream_t stream)
{
    const float* x       = (const float*)d_in[0];
    const float* w_seq1  = (const float*)d_in[1];
    const float* b_seq1  = (const float*)d_in[2];
    const float* w_seq2  = (const float*)d_in[3];
    const float* b_seq2  = (const float*)d_in[4];
    const float* w_lin   = (const float*)d_in[5];
    const float* b_lin   = (const float*)d_in[6];
    const float* w_comb  = (const float*)d_in[7];
    const float* b_comb  = (const float*)d_in[8];
    const float* w_logd  = (const float*)d_in[9];
    const float* b_logd  = (const float*)d_in[10];
    const float* w_final = (const float*)d_in[11];
    const float* b_final = (const float*)d_in[12];
    float* outp = (float*)d_out;

    const int n = in_sizes[0] / 3;            // 2,097,152 points
    const int threads = 256;
    const int total_threads = (n + 7) / 8;    // 8 points per thread
    const int blocks = (total_threads + threads - 1) / threads;

    fused_kernel<<<blocks, threads, 0, stream>>>(
        x, w_seq1, b_seq1, w_seq2, b_seq2, w_lin, b_lin, w_comb, b_comb,
        w_logd, b_logd, w_final, b_final, outp, n);
}

// Round 2
// 140.892 us; speedup vs baseline: 1.0713x; 1.0713x over previous
//
#include <hip/hip_runtime.h>

typedef float v2f __attribute__((ext_vector_type(2)));

// Fast HW transcendentals (v_exp_f32 / v_log_f32 / v_rcp_f32).
__device__ __forceinline__ float fexp2(float x) { return __builtin_amdgcn_exp2f(x); }
__device__ __forceinline__ float flog2(float x) { return __builtin_amdgcn_logf(x); }
__device__ __forceinline__ float frcp (float x) { return __builtin_amdgcn_rcpf(x); }
__device__ __forceinline__ float ffma (float a, float b, float c) { return __builtin_fmaf(a, b, c); }
__device__ __forceinline__ v2f  splat(float s) { v2f v; v.x = s; v.y = s; return v; }
__device__ __forceinline__ v2f  pkfma(v2f a, v2f b, v2f c) { return __builtin_elementwise_fma(a, b, c); }

#define LAB_EPS 0.008856f
#define F16_116 0.13793103448275862f   // 16/116
#define TANH_K  2.8853900817779268f    // 2*log2(e): exp2(K*t) = e^(2t)

// P=4 points/thread, block=256 -> 2048 blocks (8 blocks/CU, full wave slots).
// Folded algebra (once per block into LDS):
//   out = x@A + h@W2p + back_lab@Wf_bot + cvec
//   wlds[2j]   = {K*w1_0j, K*w1_1j, K*w1_2j, K*b1_j}   (tanh scale pre-folded)
//   wlds[2j+1] = {w2p_j0, w2p_j1, w2p_j2, 0}
__global__ __launch_bounds__(256) void fused_kernel(
    const float* __restrict__ x,
    const float* __restrict__ w_seq1, const float* __restrict__ b_seq1,
    const float* __restrict__ w_seq2, const float* __restrict__ b_seq2,
    const float* __restrict__ w_lin,  const float* __restrict__ b_lin,
    const float* __restrict__ w_comb, const float* __restrict__ b_comb,
    const float* __restrict__ w_logd, const float* __restrict__ b_logd,
    const float* __restrict__ w_final,const float* __restrict__ b_final,
    float* __restrict__ out, int n)
{
    __shared__ float4 wlds[128];
    __shared__ float  smlds[33];   // A[9], Wf_bot[9], w_logd[9], b_logd[3], cvec[3]

    const int tid = threadIdx.x;
    if (tid < 64) {
        const int j = tid;
        float H3[9];
        for (int i = 0; i < 3; ++i)
            for (int c = 0; c < 3; ++c) {
                float h = 0.f;
                for (int m = 0; m < 3; ++m) h += w_comb[(i + 3) * 3 + m] * w_final[m * 3 + c];
                H3[i * 3 + c] = h;
            }
        const float w0 = w_seq2[j * 3 + 0], w1 = w_seq2[j * 3 + 1], w2 = w_seq2[j * 3 + 2];
        wlds[2 * j]     = make_float4(w_seq1[j] * TANH_K, w_seq1[64 + j] * TANH_K,
                                      w_seq1[128 + j] * TANH_K, b_seq1[j] * TANH_K);
        wlds[2 * j + 1] = make_float4(w0 * H3[0] + w1 * H3[3] + w2 * H3[6],
                                      w0 * H3[1] + w1 * H3[4] + w2 * H3[7],
                                      w0 * H3[2] + w1 * H3[5] + w2 * H3[8], 0.f);
        if (j == 0) {
            float G[9];
            for (int i = 0; i < 3; ++i)
                for (int c = 0; c < 3; ++c) {
                    float gg = 0.f;
                    for (int m = 0; m < 3; ++m) gg += w_comb[i * 3 + m] * w_final[m * 3 + c];
                    G[i * 3 + c] = gg;
                }
            for (int k = 0; k < 3; ++k)
                for (int c = 0; c < 3; ++c) {
                    float s = 0.f;
                    for (int i = 0; i < 3; ++i) s += w_lin[k * 3 + i] * G[i * 3 + c];
                    smlds[k * 3 + c]      = s;                          // A
                    smlds[9  + k * 3 + c] = w_final[(k + 3) * 3 + c];   // Wf_bot
                    smlds[18 + k * 3 + c] = w_logd[k * 3 + c];
                }
            for (int c = 0; c < 3; ++c) {
                float s = b_final[c];
                for (int i = 0; i < 3; ++i)
                    s += b_lin[i] * G[i * 3 + c] + b_seq2[i] * H3[i * 3 + c]
                       + b_comb[i] * w_final[i * 3 + c];
                smlds[27 + c] = b_logd[c];
                smlds[30 + c] = s;                                      // cvec
            }
        }
    }
    __syncthreads();

    const int g = blockIdx.x * blockDim.x + tid;
    if (g * 4 >= n) return;

    // Load 4 points = 12 floats = 3 float4
    const float4* xin = reinterpret_cast<const float4*>(x) + (size_t)g * 3;
    const float4 v0 = xin[0], v1 = xin[1], v2 = xin[2];
    const float f[12] = {v0.x, v0.y, v0.z, v0.w, v1.x, v1.y, v1.z, v1.w, v2.x, v2.y, v2.z, v2.w};

    // Pack as pairs: xs2[q][c] = {pt(2q) ch c, pt(2q+1) ch c}
    v2f xs2[2][3];
#pragma unroll
    for (int q = 0; q < 2; ++q)
#pragma unroll
        for (int c = 0; c < 3; ++c) { xs2[q][c].x = f[6 * q + c]; xs2[q][c].y = f[6 * q + 3 + c]; }

    v2f acc2[2][3];
#pragma unroll
    for (int q = 0; q < 2; ++q)
#pragma unroll
        for (int c = 0; c < 3; ++c) acc2[q][c] = splat(0.f);

    // Hidden layer: h_j = tanh-of-prescaled; acc += h_j * w2p_j  (packed fp32 over pairs)
#pragma unroll 4
    for (int j = 0; j < 64; ++j) {
        const float4 wa = wlds[2 * j];
        const float4 wb = wlds[2 * j + 1];
#pragma unroll
        for (int q = 0; q < 2; ++q) {
            v2f t = pkfma(xs2[q][0], splat(wa.x),
                    pkfma(xs2[q][1], splat(wa.y),
                    pkfma(xs2[q][2], splat(wa.z), splat(wa.w))));   // = 2*log2e * (x.w1+b1)
            v2f e; e.x = fexp2(t.x); e.y = fexp2(t.y);              // e^(2t)
            v2f ep = e + splat(1.0f);
            v2f r; r.x = frcp(ep.x); r.y = frcp(ep.y);              // rcp(inf)=0 -> h=1, safe
            v2f h = pkfma(splat(-2.0f), r, splat(1.0f));            // tanh
            acc2[q][0] = pkfma(h, splat(wb.x), acc2[q][0]);
            acc2[q][1] = pkfma(h, splat(wb.y), acc2[q][1]);
            acc2[q][2] = pkfma(h, splat(wb.z), acc2[q][2]);
        }
    }

    // Epilogue constants (loaded after hot loop to keep its VGPR footprint low)
    float A[9], Wfb[9], Wld[9], bld[3], cv[3];
#pragma unroll
    for (int i = 0; i < 9; ++i) { A[i] = smlds[i]; Wfb[i] = smlds[9 + i]; Wld[i] = smlds[18 + i]; }
#pragma unroll
    for (int i = 0; i < 3; ++i) { bld[i] = smlds[27 + i]; cv[i] = smlds[30 + i]; }

    float ov[12];
#pragma unroll
    for (int p = 0; p < 4; ++p) {
        const float L  = f[3 * p + 0], aa = f[3 * p + 1], bb = f[3 * p + 2];
        const float a0 = (p & 1) ? acc2[p >> 1][0].y : acc2[p >> 1][0].x;
        const float a1 = (p & 1) ? acc2[p >> 1][1].y : acc2[p >> 1][1].x;
        const float a2 = (p & 1) ? acc2[p >> 1][2].y : acc2[p >> 1][2].x;
        // ---- lab2rgb(x) ----
        const float fy = (L + 16.0f) * (1.0f / 116.0f);
        const float fx = ffma(aa,  0.002f, fy);
        const float fz = ffma(bb, -0.005f, fy);
        float rgb[3];
        {
            const float f3x = fx * fx * fx, f3y = fy * fy * fy, f3z = fz * fz * fz;
            const float tx = f3x > LAB_EPS ? f3x : (fx - F16_116) * (1.0f / 7.787f);
            const float ty = f3y > LAB_EPS ? f3y : (fy - F16_116) * (1.0f / 7.787f);
            const float tz = f3z > LAB_EPS ? f3z : (fz - F16_116) * (1.0f / 7.787f);
            const float X = tx * 0.95047f, Y = ty, Z = tz * 1.08883f;
            const float linv[3] = {
                 3.2404542f * X - 1.5371385f * Y - 0.4985314f * Z,
                -0.9692660f * X + 1.8760108f * Y + 0.0415560f * Z,
                 0.0556434f * X - 0.2040259f * Y + 1.0572252f * Z};
#pragma unroll
            for (int c = 0; c < 3; ++c) {
                const float cc = linv[c];
                const float lo = 12.92f * cc;
                const float hi = ffma(1.055f,
                                      fexp2(flog2(fmaxf(cc, 0.0031308f)) * (1.0f / 2.4f)),
                                      -0.055f);
                rgb[c] = cc <= 0.0031308f ? lo : hi;
            }
        }
        // ---- -log10 -> @w_logd+b -> 10^ -> srgb_to_linear ----
        const float ld0 = -0.30102999566398120f * flog2(rgb[0]);
        const float ld1 = -0.30102999566398120f * flog2(rgb[1]);
        const float ld2 = -0.30102999566398120f * flog2(rgb[2]);
        float lin2[3];
#pragma unroll
        for (int c = 0; c < 3; ++c) {
            const float mp  = ffma(ld0, Wld[c], ffma(ld1, Wld[3 + c], ffma(ld2, Wld[6 + c], bld[c])));
            const float r10 = fexp2(mp * 3.3219280948873623f);   // 10^mp
            const float lo  = r10 * (1.0f / 12.92f);
            const float base = (fmaxf(r10, 0.04045f) + 0.055f) * (1.0f / 1.055f);
            const float hi  = fexp2(2.4f * flog2(base));
            lin2[c] = r10 <= 0.04045f ? lo : hi;
        }
        // ---- rgb2lab ----
        const float X2 = (0.412453f * lin2[0] + 0.357580f * lin2[1] + 0.180423f * lin2[2]) * (1.0f / 0.95047f);
        const float Y2 =  0.212671f * lin2[0] + 0.715160f * lin2[1] + 0.072169f * lin2[2];
        const float Z2 = (0.019334f * lin2[0] + 0.119193f * lin2[1] + 0.950227f * lin2[2]) * (1.0f / 1.08883f);
        const float fX = X2 > LAB_EPS ? fexp2(flog2(fmaxf(X2, LAB_EPS)) * (1.0f / 3.0f)) : ffma(7.787f, X2, F16_116);
        const float fY = Y2 > LAB_EPS ? fexp2(flog2(fmaxf(Y2, LAB_EPS)) * (1.0f / 3.0f)) : ffma(7.787f, Y2, F16_116);
        const float fZ = Z2 > LAB_EPS ? fexp2(flog2(fmaxf(Z2, LAB_EPS)) * (1.0f / 3.0f)) : ffma(7.787f, Z2, F16_116);
        const float bL = ffma(116.0f, fY, -16.0f);
        const float bA = 500.0f * (fX - fY);
        const float bB = 200.0f * (fY - fZ);
        // ---- final combine (folded) ----
#pragma unroll
        for (int c = 0; c < 3; ++c) {
            float o = cv[c];
            o = ffma(L,  A[c],     o);
            o = ffma(aa, A[3 + c], o);
            o = ffma(bb, A[6 + c], o);
            o += (c == 0 ? a0 : (c == 1 ? a1 : a2));
            o = ffma(bL, Wfb[c],     o);
            o = ffma(bA, Wfb[3 + c], o);
            o = ffma(bB, Wfb[6 + c], o);
            ov[p * 3 + c] = o;
        }
    }

    float4* op = reinterpret_cast<float4*>(out) + (size_t)g * 3;
#pragma unroll
    for (int i = 0; i < 3; ++i)
        op[i] = make_float4(ov[4 * i], ov[4 * i + 1], ov[4 * i + 2], ov[4 * i + 3]);
}

extern "C" void kernel_launch(void* const* d_in, const int* in_sizes, int n_in,
                              void* d_out, int out_size, void* d_ws, size_t ws_size,
                              hipStream_t stream)
{
    const float* x       = (const float*)d_in[0];
    const float* w_seq1  = (const float*)d_in[1];
    const float* b_seq1  = (const float*)d_in[2];
    const float* w_seq2  = (const float*)d_in[3];
    const float* b_seq2  = (const float*)d_in[4];
    const float* w_lin   = (const float*)d_in[5];
    const float* b_lin   = (const float*)d_in[6];
    const float* w_comb  = (const float*)d_in[7];
    const float* b_comb  = (const float*)d_in[8];
    const float* w_logd  = (const float*)d_in[9];
    const float* b_logd  = (const float*)d_in[10];
    const float* w_final = (const float*)d_in[11];
    const float* b_final = (const float*)d_in[12];
    float* outp = (float*)d_out;

    const int n = in_sizes[0] / 3;            // 2,097,152 points
    const int threads = 256;
    const int total_threads = (n + 3) / 4;    // 4 points per thread
    const int blocks = (total_threads + threads - 1) / threads;

    fused_kernel<<<blocks, threads, 0, stream>>>(
        x, w_seq1, b_seq1, w_seq2, b_seq2, w_lin, b_lin, w_comb, b_comb,
        w_logd, b_logd, w_final, b_final, outp, n);
}